// Round 15
// baseline (100.991 us; speedup 1.0000x reference)
//
#include <hip/hip_runtime.h>
#include <math.h>

typedef __attribute__((ext_vector_type(4))) float f32x4;
typedef _Float16 f16x8 __attribute__((ext_vector_type(8)));
typedef _Float16 f16x4v __attribute__((ext_vector_type(4)));

#define S_LEN 2048
#define D_HEAD 64
#define C2 0.18033688011112043f   /* log2(e)/8 */

static __device__ __forceinline__ float exp2v(float x) { // v_exp_f32 = 2^x
    float r; asm("v_exp_f32 %0, %1" : "=v"(r) : "v"(x)); return r;
}

static __device__ __forceinline__ void gl_lds16(const void* g, void* l) {
    __builtin_amdgcn_global_load_lds(
        (const __attribute__((address_space(1))) unsigned int*)g,
        (__attribute__((address_space(3))) unsigned int*)l, 16, 0, 0);
}

// ---- prep: T5 bias baked to [h][delta+2047], pre-scaled by log2(e)/8 ----
__global__ void prep_bias(const float* __restrict__ table, float* __restrict__ bias_d) {
    int idx = blockIdx.x * blockDim.x + threadIdx.x;   // 0..4095
    if (idx >= 4096) return;
    int delta = idx - 2047;                 // k - q
    int bpos = (delta > 0) ? 16 : 0;
    int ad = delta < 0 ? -delta : delta;
    int rel;
    if (ad < 8) {
        rel = bpos + ad;
    } else {
        float rp = (float)ad;
        int lg = 8 + (int)(logf(rp / 8.0f) / 2.772588722239781f * 8.0f);  // log(16)
        if (lg > 15) lg = 15;
        rel = bpos + lg;
    }
    #pragma unroll
    for (int h = 0; h < 4; ++h)
        bias_d[h * 4096 + idx] = C2 * table[rel * 4 + h];
}

// ---- prep: elementwise fp32 -> fp16 (for K) ----
__global__ void prep_half(const float* __restrict__ src, _Float16* __restrict__ dst) {
    size_t i8 = ((size_t)blockIdx.x * 256 + threadIdx.x) * 8;
    f32x4 a = *(const f32x4*)(src + i8);
    f32x4 b = *(const f32x4*)(src + i8 + 4);
    f16x8 h;
    h[0] = (_Float16)a[0]; h[1] = (_Float16)a[1];
    h[2] = (_Float16)a[2]; h[3] = (_Float16)a[3];
    h[4] = (_Float16)b[0]; h[5] = (_Float16)b[1];
    h[6] = (_Float16)b[2]; h[7] = (_Float16)b[3];
    *(f16x8*)(dst + i8) = h;
}

// ---- prep: V [bh][k][d] fp32  ->  V^T fp16 [bh][d][k] ----
__global__ void prep_vt(const float* __restrict__ V, _Float16* __restrict__ vt) {
    __shared__ float tile[64][65];
    const int bh = blockIdx.y;
    const int k0 = blockIdx.x * 64;
    const int t = threadIdx.x;
    {
        int r = t >> 2, c0 = (t & 3) * 16;
        const float* src = V + ((size_t)bh * S_LEN + k0 + r) * D_HEAD + c0;
        #pragma unroll
        for (int i = 0; i < 16; i += 4) {
            f32x4 v = *(const f32x4*)(src + i);
            tile[r][c0 + i + 0] = v[0];
            tile[r][c0 + i + 1] = v[1];
            tile[r][c0 + i + 2] = v[2];
            tile[r][c0 + i + 3] = v[3];
        }
    }
    __syncthreads();
    {
        int d = t >> 2, kc = (t & 3) * 16;
        size_t ob = ((size_t)bh * D_HEAD + d) * S_LEN + k0 + kc;
        #pragma unroll
        for (int half = 0; half < 2; ++half) {
            f16x8 hv;
            #pragma unroll
            for (int i = 0; i < 8; ++i)
                hv[i] = (_Float16)tile[kc + half * 8 + i][d];
            *(f16x8*)(vt + ob + half * 8) = hv;
        }
    }
}

// ============================================================================
// main: two-pass fused attention, log2-domain max-free softmax, all-fp16.
// r14 EXACTLY, one change: P1 is TRIPLE-BUFFERED ([0,48K), slot t%3; slot 2
// overlaps the P2-only pball region). Prologue stages tiles 0+1, ends
// vmcnt(2)+barrier. Iter t stages tile t+2; the in-order queue
// [t+1 staging][mb][t+2 staging] means the compiler's mb-load waits retire
// t+1 automatically; end-of-iter wait becomes vmcnt(2) (t+2 rides) instead
// of vmcnt(0). Issue-to-consume distance 1 -> 2 iters: covers HBM/L2
// latency that stalled every P1 iter. P2/flush/math/epilogue unchanged.
// LDS 53760B, 3 blocks/CU unchanged.
// ============================================================================
__launch_bounds__(512, 6)
__global__ void attn_main(const float* __restrict__ Q, const int* __restrict__ mask,
                          const float* __restrict__ bias2,
                          const _Float16* __restrict__ kh_g,
                          const _Float16* __restrict__ vt_g,
                          float* __restrict__ outp, float* __restrict__ p_out) {
    __shared__ __align__(16) char smem[53760];
    _Float16* pball = (_Float16*)(smem + 32768);   // 8 x 2 x 640 f16 (P2 only)
    float* stats = (float*)(smem + 53248);         // 128 floats

    const int tid = threadIdx.x;
    const int w = tid >> 6, l = tid & 63;
    const int wq = w & 3, wk = w >> 2;
    const int g = l >> 4, lq = l & 15;
    const int r7 = lq & 7;
    const int bid = blockIdx.x;
    const int bh = bid & 15, b = bh >> 2, h = bh & 3;   // bid%8 == bh%8: bh pinned per XCD
    const int q0 = (bid >> 4) * 64;

    const float* Qp = Q + (size_t)bh * (S_LEN * D_HEAD);
    const int* mp = mask + b * S_LEN;
    const _Float16* khp = kh_g + (size_t)bh * (S_LEN * D_HEAD);
    const _Float16* vhp = vt_g + (size_t)bh * (S_LEN * D_HEAD);

    // ---- stage Q -> f16 (swizzled ds_write) at smem[0..8K) ----
    _Float16* qarea = (_Float16*)smem;
    {
        int sr = tid >> 3, tb = tid & 7;
        const float* src = Qp + (size_t)(q0 + sr) * D_HEAD + tb * 8;
        f32x4 a = *(const f32x4*)src;
        f32x4 c = *(const f32x4*)(src + 4);
        f16x8 hv;
        hv[0] = (_Float16)a[0]; hv[1] = (_Float16)a[1];
        hv[2] = (_Float16)a[2]; hv[3] = (_Float16)a[3];
        hv[4] = (_Float16)c[0]; hv[5] = (_Float16)c[1];
        hv[6] = (_Float16)c[2]; hv[7] = (_Float16)c[3];
        *(f16x8*)(qarea + sr * 64 + ((tb ^ (sr & 7)) * 8)) = hv;
    }
    __syncthreads();
    f16x8 qf[2];
    const int qrow = 16 * wq + lq;
    #pragma unroll
    for (int c = 0; c < 2; ++c)
        qf[c] = *(const f16x8*)(qarea + qrow * 64 + ((4 * c + g) ^ r7) * 8);
    __syncthreads();   // all Q reads done before staging overwrites [0..8K)

    const int qq = q0 + qrow;

    // hoisted staging geometry
    const int rr3 = tid >> 3;                       // chunk row 0..63
    const int ub0 = (((tid & 7) ^ (rr3 & 7)) * 8);  // swizzled 8-elem block
    // pass-1 prologue: stage K tiles 0 AND 1 -> buf0,buf1 (triple-buffer)
    const _Float16* s1a = khp + (size_t)rr3 * 64 + ub0;
    gl_lds16(s1a,         smem + tid * 16);
    gl_lds16(s1a + 4096,  smem + 8192  + tid * 16);
    gl_lds16(s1a + 8192,  smem + 16384 + tid * 16);
    gl_lds16(s1a + 12288, smem + 24576 + tid * 16);
    s1a += 16384;   // next tile to stage = tile 2
    asm volatile("s_waitcnt vmcnt(2)" ::: "memory");   // tile0 landed, tile1 rides
    __builtin_amdgcn_sched_barrier(0);
    __builtin_amdgcn_s_barrier();
    __builtin_amdgcn_sched_barrier(0);

    // ================= PASS 1: l = sum(2^s2), K-tile 128, 16 iters, tbuf =================
    const int* mP1 = mp + 64 * wk + 4 * g;
    const float* bP1 = bias2 + h * 4096 + 2047 - qq + 64 * wk + 4 * g;
    float lsum = 0.0f;
    int bcur = 0;
    for (int t = 0; t < 16; ++t) {
        const char* kb = smem + bcur * 16384;
        int4 mv[4]; f32x4 bv[4];
        #pragma unroll
        for (int t2 = 0; t2 < 4; ++t2) {
            mv[t2] = *(const int4*)(mP1 + 16 * t2);
            bv[t2] = *(const f32x4*)(bP1 + 16 * t2);
        }
        if (t < 14) {   // stage tile t+2 into buffer (bcur+2)%3
            int bn = bcur + 2; if (bn >= 3) bn -= 3;
            char* nb = smem + bn * 16384 + tid * 16;
            gl_lds16(s1a, nb);
            gl_lds16(s1a + 4096, nb + 8192);
            s1a += 8192;
        }
        __builtin_amdgcn_sched_barrier(0);
        #pragma unroll
        for (int t2 = 0; t2 < 4; ++t2) {
            const int krow = 64 * wk + 16 * t2 + lq;
            f32x4 acc = {0.f, 0.f, 0.f, 0.f};
            #pragma unroll
            for (int c = 0; c < 2; ++c) {
                f16x8 af = *(const f16x8*)(kb + krow * 128 + ((4 * c + g) ^ r7) * 16);
                acc = __builtin_amdgcn_mfma_f32_16x16x32_f16(af, qf[c], acc, 0, 0, 0);
            }
            float s0 = mv[t2].x ? fmaf(acc[0], C2, bv[t2][0]) : -1e9f;
            float s1 = mv[t2].y ? fmaf(acc[1], C2, bv[t2][1]) : -1e9f;
            float s2 = mv[t2].z ? fmaf(acc[2], C2, bv[t2][2]) : -1e9f;
            float s3 = mv[t2].w ? fmaf(acc[3], C2, bv[t2][3]) : -1e9f;
            lsum += exp2v(s0) + exp2v(s1) + exp2v(s2) + exp2v(s3);
        }
        mP1 += 128; bP1 += 128;
        // t+1's staging already retired by the mb-load waits (older in queue);
        // leave t+2's 2 loads riding
        if (t < 14) { asm volatile("s_waitcnt vmcnt(2)" ::: "memory"); }
        else        { asm volatile("s_waitcnt vmcnt(0)" ::: "memory"); }
        __builtin_amdgcn_sched_barrier(0);
        __builtin_amdgcn_s_barrier();
        __builtin_amdgcn_sched_barrier(0);
        bcur = (bcur == 2) ? 0 : bcur + 1;
    }
    lsum += __shfl_xor(lsum, 16);
    lsum += __shfl_xor(lsum, 32);
    if (g == 0) stats[wk * 64 + qrow] = lsum;

    // ---- pass-2 staging pointers + prologue (buf0: K64, V64) ----
    const _Float16* sKh = khp + (size_t)rr3 * 64 + ub0;
    const _Float16* sVh = vhp + (size_t)rr3 * 2048 + ub0;
    gl_lds16(sKh, smem + tid * 16);
    gl_lds16(sVh, smem + 8192 + tid * 16);
    __syncthreads();   // stats visible + buf0 staged (full drain, once)
    float lr2q;
    {
        float L = stats[qrow] + stats[64 + qrow];
        float lg; asm("v_log_f32 %0, %1" : "=v"(lg) : "v"(L));
        lr2q = -lg;    // p = 2^(s2 + lr2q)
    }

    // ================= PASS 2: 2-slot p, wq-pair 256B-run flush =================
    f32x4 acco[4] = {{0.f,0.f,0.f,0.f},{0.f,0.f,0.f,0.f},{0.f,0.f,0.f,0.f},{0.f,0.f,0.f,0.f}};
    const int* mP = mp + 32 * wk + 4 * g;
    const float* bP = bias2 + h * 4096 + 2047 - qq + 32 * wk + 4 * g;
    const int kAoff0 = (32 * wk + lq) * 128;               // K frag byte base (+t2*2048)
    const int voffb = lq * 128 + ((4 * wk + g) ^ r7) * 16; // V frag byte base (+n*2048)
    // p-buffer (2 slots per wave): base + slot*640
    _Float16* pwr = pball + w * 1280 + lq * 40 + g * 4;          // + slot*640 + 16*t2
    const _Float16* prd = pball + w * 1280 + lq * 40 + g * 8;    // + slot*640
    // flush: lane's k-half picks the (wq, h2) buffer; 2 stores x (4 rows x 256B)
    const _Float16* flb = pball + ((((l >> 3) & 1) * 4 + wq) * 1280)
                        + (8 * wk + (l >> 4)) * 40 + (l & 7) * 4;   // + ps*640 + i*160
    float* pF = p_out + (size_t)bh * (S_LEN * S_LEN)
              + (size_t)(q0 + 16 * wq + 8 * wk + (l >> 4)) * S_LEN + (l & 15) * 4;

    for (int t = 0; t < 32; ++t) {
        const int cb = (t & 1) * 16384;
        const int cs = (t & 1) * 640;          // current slot
        int4 mv[2]; f32x4 bv[2];
        #pragma unroll
        for (int t2 = 0; t2 < 2; ++t2) {
            mv[t2] = *(const int4*)(mP + 16 * t2);
            bv[t2] = *(const f32x4*)(bP + 16 * t2);
        }
        if (t < 31) {
            sKh += 4096; sVh += 64;
            char* d0 = smem + ((t + 1) & 1) * 16384 + tid * 16;
            gl_lds16(sKh, d0);
            gl_lds16(sVh, d0 + 8192);
        }
        // flush tile t-1 from slot cs^640 (stores NEWEST in queue; prev-iter
        // barrier + lgkmcnt(0) made all waves' p visible)
        if (t > 0) {
            const int ps = cs ^ 640;
            #pragma unroll
            for (int i = 0; i < 2; ++i) {
                f16x4v v = *(const f16x4v*)(flb + ps + i * 160);
                f32x4 wv;
                wv[0] = (float)v[0]; wv[1] = (float)v[1];
                wv[2] = (float)v[2]; wv[3] = (float)v[3];
                *(f32x4*)(pF + (size_t)(4 * i) * S_LEN) = wv;
            }
            pF += 64;
        }
        __builtin_amdgcn_sched_barrier(0);
        #pragma unroll
        for (int t2 = 0; t2 < 2; ++t2) {
            const char* kbase = smem + cb + kAoff0 + t2 * 2048;
            f32x4 acc = {0.f, 0.f, 0.f, 0.f};
            #pragma unroll
            for (int c = 0; c < 2; ++c) {
                f16x8 ah = *(const f16x8*)(kbase + ((4 * c + g) ^ r7) * 16);
                acc = __builtin_amdgcn_mfma_f32_16x16x32_f16(ah, qf[c], acc, 0, 0, 0);
            }
            float p0 = exp2v(mv[t2].x ? fmaf(acc[0], C2, bv[t2][0]) + lr2q : -1e9f);
            float p1 = exp2v(mv[t2].y ? fmaf(acc[1], C2, bv[t2][1]) + lr2q : -1e9f);
            float p2 = exp2v(mv[t2].z ? fmaf(acc[2], C2, bv[t2][2]) + lr2q : -1e9f);
            float p3 = exp2v(mv[t2].w ? fmaf(acc[3], C2, bv[t2][3]) + lr2q : -1e9f);
            f16x4v ph;
            ph[0] = (_Float16)p0; ph[1] = (_Float16)p1;
            ph[2] = (_Float16)p2; ph[3] = (_Float16)p3;
            *(f16x4v*)(pwr + cs + 16 * t2) = ph;   // p -> own slot
        }
        // PV: A = P [16q x 32k] (own slot), B = V^T f16
        const f16x8 pf = *(const f16x8*)(prd + cs);
        #pragma unroll
        for (int n = 0; n < 4; ++n) {
            const f16x8 bhf = *(const f16x8*)(smem + cb + 8192 + voffb + n * 2048);
            acco[n] = __builtin_amdgcn_mfma_f32_16x16x32_f16(pf, bhf, acco[n], 0, 0, 0);
        }
        mP += 64; bP += 64;
        // end-of-iter: staging retired (2 flush stores ride); lgkm drained so
        // next iter's cross-wave flush reads see this iter's p
        asm volatile("s_waitcnt vmcnt(2) lgkmcnt(0)" ::: "memory");
        __builtin_amdgcn_sched_barrier(0);
        __builtin_amdgcn_s_barrier();
        __builtin_amdgcn_sched_barrier(0);
    }
    // final flush: tile 31, slot 1 (last end-of-iter barrier made p visible)
    {
        #pragma unroll
        for (int i = 0; i < 2; ++i) {
            f16x4v v = *(const f16x4v*)(flb + 640 + i * 160);
            f32x4 wv;
            wv[0] = (float)v[0]; wv[1] = (float)v[1];
            wv[2] = (float)v[2]; wv[3] = (float)v[3];
            *(f32x4*)(pF + (size_t)(4 * i) * S_LEN) = wv;
        }
    }

    // ---- reduce the two wk halves (stage area is dead) and store out ----
    float* ored = (float*)smem;    // [64 q][64 d]
    __syncthreads();
    if (wk == 1) {
        #pragma unroll
        for (int n = 0; n < 4; ++n)
            #pragma unroll
            for (int r = 0; r < 4; ++r)
                ored[(wq * 16 + 4 * g + r) * 64 + 16 * n + lq] = acco[n][r];
    }
    __syncthreads();
    if (wk == 0) {
        #pragma unroll
        for (int n = 0; n < 4; ++n) {
            #pragma unroll
            for (int r = 0; r < 4; ++r) {
                float v = acco[n][r] + ored[(wq * 16 + 4 * g + r) * 64 + 16 * n + lq];
                outp[((size_t)bh * S_LEN + q0 + 16 * wq + 4 * g + r) * D_HEAD + 16 * n + lq] = v;
            }
        }
    }
}

extern "C" void kernel_launch(void* const* d_in, const int* in_sizes, int n_in,
                              void* d_out, int out_size, void* d_ws, size_t ws_size,
                              hipStream_t stream) {
    const float* Q = (const float*)d_in[0];
    const float* K = (const float*)d_in[1];
    const float* V = (const float*)d_in[2];
    const int* mask = (const int*)d_in[3];
    const float* table = (const float*)d_in[4];

    float* outp = (float*)d_out;
    float* p_out = outp + (size_t)4 * 4 * 2048 * 64;   // out first, then p_attn

    float* bias_d = (float*)d_ws;                                   // 64 KB
    _Float16* kh = (_Float16*)((char*)d_ws + 65536);                // 4 MB
    _Float16* vt = kh + (size_t)16 * S_LEN * D_HEAD;                // 4 MB

    prep_bias<<<16, 256, 0, stream>>>(table, bias_d);
    prep_half<<<1024, 256, 0, stream>>>(K, kh);
    prep_vt<<<dim3(32, 16), 256, 0, stream>>>(V, vt);
    attn_main<<<512, 512, 0, stream>>>(Q, mask, bias_d, kh, vt, outp, p_out);
}

// Round 16
// 97.315 us; speedup vs baseline: 1.0378x; 1.0378x over previous
//
#include <hip/hip_runtime.h>
#include <math.h>

typedef __attribute__((ext_vector_type(4))) float f32x4;
typedef _Float16 f16x8 __attribute__((ext_vector_type(8)));
typedef _Float16 f16x4v __attribute__((ext_vector_type(4)));

#define S_LEN 2048
#define D_HEAD 64
#define C2 0.18033688011112043f   /* log2(e)/8 */

static __device__ __forceinline__ float exp2v(float x) { // v_exp_f32 = 2^x
    float r; asm("v_exp_f32 %0, %1" : "=v"(r) : "v"(x)); return r;
}

static __device__ __forceinline__ void gl_lds16(const void* g, void* l) {
    __builtin_amdgcn_global_load_lds(
        (const __attribute__((address_space(1))) unsigned int*)g,
        (__attribute__((address_space(3))) unsigned int*)l, 16, 0, 0);
}

// ---- fused prep: K->fp16 (bid<1024), V->V^T fp16 (1024..1535), bias (1536+) ----
__global__ void prep_all(const float* __restrict__ K, const float* __restrict__ V,
                         const float* __restrict__ table,
                         _Float16* __restrict__ kh, _Float16* __restrict__ vt,
                         float* __restrict__ bias_d) {
    __shared__ float tile[64][65];
    const int bid = blockIdx.x;
    const int t = threadIdx.x;
    if (bid < 1024) {                       // K: fp32 -> fp16, 8 elems/thread
        size_t i8 = ((size_t)bid * 256 + t) * 8;
        f32x4 a = *(const f32x4*)(K + i8);
        f32x4 b = *(const f32x4*)(K + i8 + 4);
        f16x8 h;
        h[0] = (_Float16)a[0]; h[1] = (_Float16)a[1];
        h[2] = (_Float16)a[2]; h[3] = (_Float16)a[3];
        h[4] = (_Float16)b[0]; h[5] = (_Float16)b[1];
        h[6] = (_Float16)b[2]; h[7] = (_Float16)b[3];
        *(f16x8*)(kh + i8) = h;
    } else if (bid < 1536) {                // V [bh][k][d] -> V^T fp16 [bh][d][k]
        const int vb = bid - 1024;
        const int bh = vb >> 5;
        const int k0 = (vb & 31) * 64;
        {
            int r = t >> 2, c0 = (t & 3) * 16;
            const float* src = V + ((size_t)bh * S_LEN + k0 + r) * D_HEAD + c0;
            #pragma unroll
            for (int i = 0; i < 16; i += 4) {
                f32x4 v = *(const f32x4*)(src + i);
                tile[r][c0 + i + 0] = v[0];
                tile[r][c0 + i + 1] = v[1];
                tile[r][c0 + i + 2] = v[2];
                tile[r][c0 + i + 3] = v[3];
            }
        }
        __syncthreads();
        {
            int d = t >> 2, kc = (t & 3) * 16;
            size_t ob = ((size_t)bh * D_HEAD + d) * S_LEN + k0 + kc;
            #pragma unroll
            for (int half = 0; half < 2; ++half) {
                f16x8 hv;
                #pragma unroll
                for (int i = 0; i < 8; ++i)
                    hv[i] = (_Float16)tile[kc + half * 8 + i][d];
                *(f16x8*)(vt + ob + half * 8) = hv;
            }
        }
    } else {                                // T5 bias, pre-scaled by log2(e)/8
        int idx = (bid - 1536) * 256 + t;   // 0..4095
        if (idx < 4096) {
            int delta = idx - 2047;
            int bpos = (delta > 0) ? 16 : 0;
            int ad = delta < 0 ? -delta : delta;
            int rel;
            if (ad < 8) {
                rel = bpos + ad;
            } else {
                float rp = (float)ad;
                int lg = 8 + (int)(logf(rp / 8.0f) / 2.772588722239781f * 8.0f);
                if (lg > 15) lg = 15;
                rel = bpos + lg;
            }
            #pragma unroll
            for (int hh = 0; hh < 4; ++hh)
                bias_d[hh * 4096 + idx] = C2 * table[rel * 4 + hh];
        }
    }
}

// ============================================================================
// main: two-pass fused attention, log2-domain max-free softmax, all-fp16.
// r14's P2/store path byte-for-byte; one change: P1 uses 256-ROW K-tiles
// (8 iters, dbuf 2x32K at [0,64K)) -> half the barrier+vmcnt(0) drains.
// The P2-only pball region [32K,52.5K) overlays P1 buffer 1 (dead by P2);
// stats at 64K (dedicated). LDS 66048B -> 2 blocks/CU (= actual residency
// of grid 512 on 256 CUs; no occupancy change vs r14).
// ============================================================================
__launch_bounds__(512, 4)
__global__ void attn_main(const float* __restrict__ Q, const int* __restrict__ mask,
                          const float* __restrict__ bias2,
                          const _Float16* __restrict__ kh_g,
                          const _Float16* __restrict__ vt_g,
                          float* __restrict__ outp, float* __restrict__ p_out) {
    __shared__ __align__(16) char smem[66048];
    _Float16* pball = (_Float16*)(smem + 32768);   // 8 x 2 x 640 f16 (P2 only)
    float* stats = (float*)(smem + 65536);         // 128 floats (dedicated)

    const int tid = threadIdx.x;
    const int w = tid >> 6, l = tid & 63;
    const int wq = w & 3, wk = w >> 2;
    const int g = l >> 4, lq = l & 15;
    const int r7 = lq & 7;
    const int bid = blockIdx.x;
    const int bh = bid & 15, b = bh >> 2, h = bh & 3;   // bid%8 == bh%8: bh pinned per XCD
    const int q0 = (bid >> 4) * 64;

    const float* Qp = Q + (size_t)bh * (S_LEN * D_HEAD);
    const int* mp = mask + b * S_LEN;
    const _Float16* khp = kh_g + (size_t)bh * (S_LEN * D_HEAD);
    const _Float16* vhp = vt_g + (size_t)bh * (S_LEN * D_HEAD);

    // ---- stage Q -> f16 (swizzled ds_write) at smem[0..8K) ----
    _Float16* qarea = (_Float16*)smem;
    {
        int sr = tid >> 3, tb = tid & 7;
        const float* src = Qp + (size_t)(q0 + sr) * D_HEAD + tb * 8;
        f32x4 a = *(const f32x4*)src;
        f32x4 c = *(const f32x4*)(src + 4);
        f16x8 hv;
        hv[0] = (_Float16)a[0]; hv[1] = (_Float16)a[1];
        hv[2] = (_Float16)a[2]; hv[3] = (_Float16)a[3];
        hv[4] = (_Float16)c[0]; hv[5] = (_Float16)c[1];
        hv[6] = (_Float16)c[2]; hv[7] = (_Float16)c[3];
        *(f16x8*)(qarea + sr * 64 + ((tb ^ (sr & 7)) * 8)) = hv;
    }
    __syncthreads();
    f16x8 qf[2];
    const int qrow = 16 * wq + lq;
    #pragma unroll
    for (int c = 0; c < 2; ++c)
        qf[c] = *(const f16x8*)(qarea + qrow * 64 + ((4 * c + g) ^ r7) * 8);
    __syncthreads();   // all Q reads done before staging overwrites [0..8K)

    const int qq = q0 + qrow;

    // hoisted staging geometry
    const int rr3 = tid >> 3;                       // chunk row 0..63
    const int ub0 = (((tid & 7) ^ (rr3 & 7)) * 8);  // swizzled 8-elem block
    // pass-1 prologue: stage K rows 0..255 (tile 0, 32KB) -> smem[0..32K)
    const _Float16* s1a = khp + (size_t)rr3 * 64 + ub0;
    gl_lds16(s1a,          smem + tid * 16);
    gl_lds16(s1a + 4096,   smem + 8192  + tid * 16);
    gl_lds16(s1a + 8192,   smem + 16384 + tid * 16);
    gl_lds16(s1a + 12288,  smem + 24576 + tid * 16);
    __syncthreads();   // full drain, once

    // ================= PASS 1: l = sum(2^s2), K-tile 256, 8 iters =================
    const int* mP1 = mp + 128 * wk + 4 * g;
    const float* bP1 = bias2 + h * 4096 + 2047 - qq + 128 * wk + 4 * g;
    float lsum = 0.0f;
    for (int t = 0; t < 8; ++t) {
        const char* kb = smem + (t & 1) * 32768;
        int4 mv[8]; f32x4 bv[8];
        #pragma unroll
        for (int t2 = 0; t2 < 8; ++t2) {
            mv[t2] = *(const int4*)(mP1 + 16 * t2);
            bv[t2] = *(const f32x4*)(bP1 + 16 * t2);
        }
        if (t < 7) {   // stage tile t+1 (4 x 8KB)
            s1a += 16384;
            char* nb = smem + ((t + 1) & 1) * 32768 + tid * 16;
            gl_lds16(s1a, nb);
            gl_lds16(s1a + 4096, nb + 8192);
            gl_lds16(s1a + 8192, nb + 16384);
            gl_lds16(s1a + 12288, nb + 24576);
        }
        __builtin_amdgcn_sched_barrier(0);
        #pragma unroll
        for (int t2 = 0; t2 < 8; ++t2) {
            const int krow = 128 * wk + 16 * t2 + lq;
            f32x4 acc = {0.f, 0.f, 0.f, 0.f};
            #pragma unroll
            for (int c = 0; c < 2; ++c) {
                f16x8 af = *(const f16x8*)(kb + krow * 128 + ((4 * c + g) ^ r7) * 16);
                acc = __builtin_amdgcn_mfma_f32_16x16x32_f16(af, qf[c], acc, 0, 0, 0);
            }
            float s0 = mv[t2].x ? fmaf(acc[0], C2, bv[t2][0]) : -1e9f;
            float s1 = mv[t2].y ? fmaf(acc[1], C2, bv[t2][1]) : -1e9f;
            float s2 = mv[t2].z ? fmaf(acc[2], C2, bv[t2][2]) : -1e9f;
            float s3 = mv[t2].w ? fmaf(acc[3], C2, bv[t2][3]) : -1e9f;
            lsum += exp2v(s0) + exp2v(s1) + exp2v(s2) + exp2v(s3);
        }
        mP1 += 256; bP1 += 256;
        asm volatile("s_waitcnt vmcnt(0)" ::: "memory");
        __builtin_amdgcn_sched_barrier(0);
        __builtin_amdgcn_s_barrier();
        __builtin_amdgcn_sched_barrier(0);
    }
    lsum += __shfl_xor(lsum, 16);
    lsum += __shfl_xor(lsum, 32);
    if (g == 0) stats[wk * 64 + qrow] = lsum;

    // ---- pass-2 staging pointers + prologue (buf0: K64, V64) ----
    const _Float16* sKh = khp + (size_t)rr3 * 64 + ub0;
    const _Float16* sVh = vhp + (size_t)rr3 * 2048 + ub0;
    gl_lds16(sKh, smem + tid * 16);
    gl_lds16(sVh, smem + 8192 + tid * 16);
    __syncthreads();   // stats visible + buf0 staged (full drain, once)
    float lr2q;
    {
        float L = stats[qrow] + stats[64 + qrow];
        float lg; asm("v_log_f32 %0, %1" : "=v"(lg) : "v"(L));
        lr2q = -lg;    // p = 2^(s2 + lr2q)
    }

    // ================= PASS 2: 2-slot p, wq-pair 256B-run flush (r14) =================
    f32x4 acco[4] = {{0.f,0.f,0.f,0.f},{0.f,0.f,0.f,0.f},{0.f,0.f,0.f,0.f},{0.f,0.f,0.f,0.f}};
    const int* mP = mp + 32 * wk + 4 * g;
    const float* bP = bias2 + h * 4096 + 2047 - qq + 32 * wk + 4 * g;
    const int kAoff0 = (32 * wk + lq) * 128;               // K frag byte base (+t2*2048)
    const int voffb = lq * 128 + ((4 * wk + g) ^ r7) * 16; // V frag byte base (+n*2048)
    // p-buffer (2 slots per wave): base + slot*640
    _Float16* pwr = pball + w * 1280 + lq * 40 + g * 4;          // + slot*640 + 16*t2
    const _Float16* prd = pball + w * 1280 + lq * 40 + g * 8;    // + slot*640
    // flush: lane's k-half picks the (wq, h2) buffer; 2 stores x (4 rows x 256B)
    const _Float16* flb = pball + ((((l >> 3) & 1) * 4 + wq) * 1280)
                        + (8 * wk + (l >> 4)) * 40 + (l & 7) * 4;   // + ps*640 + i*160
    float* pF = p_out + (size_t)bh * (S_LEN * S_LEN)
              + (size_t)(q0 + 16 * wq + 8 * wk + (l >> 4)) * S_LEN + (l & 15) * 4;

    for (int t = 0; t < 32; ++t) {
        const int cb = (t & 1) * 16384;
        const int cs = (t & 1) * 640;          // current slot
        int4 mv[2]; f32x4 bv[2];
        #pragma unroll
        for (int t2 = 0; t2 < 2; ++t2) {
            mv[t2] = *(const int4*)(mP + 16 * t2);
            bv[t2] = *(const f32x4*)(bP + 16 * t2);
        }
        if (t < 31) {
            sKh += 4096; sVh += 64;
            char* d0 = smem + ((t + 1) & 1) * 16384 + tid * 16;
            gl_lds16(sKh, d0);
            gl_lds16(sVh, d0 + 8192);
        }
        // flush tile t-1 from slot cs^640 (stores NEWEST in queue; prev-iter
        // barrier + lgkmcnt(0) made all waves' p visible)
        if (t > 0) {
            const int ps = cs ^ 640;
            #pragma unroll
            for (int i = 0; i < 2; ++i) {
                f16x4v v = *(const f16x4v*)(flb + ps + i * 160);
                f32x4 wv;
                wv[0] = (float)v[0]; wv[1] = (float)v[1];
                wv[2] = (float)v[2]; wv[3] = (float)v[3];
                *(f32x4*)(pF + (size_t)(4 * i) * S_LEN) = wv;
            }
            pF += 64;
        }
        __builtin_amdgcn_sched_barrier(0);
        #pragma unroll
        for (int t2 = 0; t2 < 2; ++t2) {
            const char* kbase = smem + cb + kAoff0 + t2 * 2048;
            f32x4 acc = {0.f, 0.f, 0.f, 0.f};
            #pragma unroll
            for (int c = 0; c < 2; ++c) {
                f16x8 ah = *(const f16x8*)(kbase + ((4 * c + g) ^ r7) * 16);
                acc = __builtin_amdgcn_mfma_f32_16x16x32_f16(ah, qf[c], acc, 0, 0, 0);
            }
            float p0 = exp2v(mv[t2].x ? fmaf(acc[0], C2, bv[t2][0]) + lr2q : -1e9f);
            float p1 = exp2v(mv[t2].y ? fmaf(acc[1], C2, bv[t2][1]) + lr2q : -1e9f);
            float p2 = exp2v(mv[t2].z ? fmaf(acc[2], C2, bv[t2][2]) + lr2q : -1e9f);
            float p3 = exp2v(mv[t2].w ? fmaf(acc[3], C2, bv[t2][3]) + lr2q : -1e9f);
            f16x4v ph;
            ph[0] = (_Float16)p0; ph[1] = (_Float16)p1;
            ph[2] = (_Float16)p2; ph[3] = (_Float16)p3;
            *(f16x4v*)(pwr + cs + 16 * t2) = ph;   // p -> own slot
        }
        // PV: A = P [16q x 32k] (own slot), B = V^T f16
        const f16x8 pf = *(const f16x8*)(prd + cs);
        #pragma unroll
        for (int n = 0; n < 4; ++n) {
            const f16x8 bhf = *(const f16x8*)(smem + cb + 8192 + voffb + n * 2048);
            acco[n] = __builtin_amdgcn_mfma_f32_16x16x32_f16(pf, bhf, acco[n], 0, 0, 0);
        }
        mP += 64; bP += 64;
        // end-of-iter: staging retired (2 flush stores ride); lgkm drained so
        // next iter's cross-wave flush reads see this iter's p
        asm volatile("s_waitcnt vmcnt(2) lgkmcnt(0)" ::: "memory");
        __builtin_amdgcn_sched_barrier(0);
        __builtin_amdgcn_s_barrier();
        __builtin_amdgcn_sched_barrier(0);
    }
    // final flush: tile 31, slot 1 (last end-of-iter barrier made p visible)
    {
        #pragma unroll
        for (int i = 0; i < 2; ++i) {
            f16x4v v = *(const f16x4v*)(flb + 640 + i * 160);
            f32x4 wv;
            wv[0] = (float)v[0]; wv[1] = (float)v[1];
            wv[2] = (float)v[2]; wv[3] = (float)v[3];
            *(f32x4*)(pF + (size_t)(4 * i) * S_LEN) = wv;
        }
    }

    // ---- reduce the two wk halves (stage area is dead) and store out ----
    float* ored = (float*)smem;    // [64 q][64 d]
    __syncthreads();
    if (wk == 1) {
        #pragma unroll
        for (int n = 0; n < 4; ++n)
            #pragma unroll
            for (int r = 0; r < 4; ++r)
                ored[(wq * 16 + 4 * g + r) * 64 + 16 * n + lq] = acco[n][r];
    }
    __syncthreads();
    if (wk == 0) {
        #pragma unroll
        for (int n = 0; n < 4; ++n) {
            #pragma unroll
            for (int r = 0; r < 4; ++r) {
                float v = acco[n][r] + ored[(wq * 16 + 4 * g + r) * 64 + 16 * n + lq];
                outp[((size_t)bh * S_LEN + q0 + 16 * wq + 4 * g + r) * D_HEAD + 16 * n + lq] = v;
            }
        }
    }
}

extern "C" void kernel_launch(void* const* d_in, const int* in_sizes, int n_in,
                              void* d_out, int out_size, void* d_ws, size_t ws_size,
                              hipStream_t stream) {
    const float* Q = (const float*)d_in[0];
    const float* K = (const float*)d_in[1];
    const float* V = (const float*)d_in[2];
    const int* mask = (const int*)d_in[3];
    const float* table = (const float*)d_in[4];

    float* outp = (float*)d_out;
    float* p_out = outp + (size_t)4 * 4 * 2048 * 64;   // out first, then p_attn

    float* bias_d = (float*)d_ws;                                   // 64 KB
    _Float16* kh = (_Float16*)((char*)d_ws + 65536);                // 4 MB
    _Float16* vt = kh + (size_t)16 * S_LEN * D_HEAD;                // 4 MB

    prep_all<<<1552, 256, 0, stream>>>(K, V, table, kh, vt, bias_d);
    attn_main<<<512, 512, 0, stream>>>(Q, mask, bias_d, kh, vt, outp, p_out);
}

// Round 17
// 92.446 us; speedup vs baseline: 1.0924x; 1.0527x over previous
//
#include <hip/hip_runtime.h>
#include <math.h>

typedef __attribute__((ext_vector_type(4))) float f32x4;
typedef _Float16 f16x8 __attribute__((ext_vector_type(8)));
typedef _Float16 f16x4v __attribute__((ext_vector_type(4)));

#define S_LEN 2048
#define D_HEAD 64
#define C2 0.18033688011112043f   /* log2(e)/8 */

static __device__ __forceinline__ float exp2v(float x) { // v_exp_f32 = 2^x
    float r; asm("v_exp_f32 %0, %1" : "=v"(r) : "v"(x)); return r;
}

static __device__ __forceinline__ void gl_lds16(const void* g, void* l) {
    __builtin_amdgcn_global_load_lds(
        (const __attribute__((address_space(1))) unsigned int*)g,
        (__attribute__((address_space(3))) unsigned int*)l, 16, 0, 0);
}

// ---- prep: T5 bias baked to [h][delta+2047], pre-scaled by log2(e)/8 ----
__global__ void prep_bias(const float* __restrict__ table, float* __restrict__ bias_d) {
    int idx = blockIdx.x * blockDim.x + threadIdx.x;   // 0..4095
    if (idx >= 4096) return;
    int delta = idx - 2047;                 // k - q
    int bpos = (delta > 0) ? 16 : 0;
    int ad = delta < 0 ? -delta : delta;
    int rel;
    if (ad < 8) {
        rel = bpos + ad;
    } else {
        float rp = (float)ad;
        int lg = 8 + (int)(logf(rp / 8.0f) / 2.772588722239781f * 8.0f);  // log(16)
        if (lg > 15) lg = 15;
        rel = bpos + lg;
    }
    #pragma unroll
    for (int h = 0; h < 4; ++h)
        bias_d[h * 4096 + idx] = C2 * table[rel * 4 + h];
}

// ---- prep: elementwise fp32 -> fp16 (for K) ----
__global__ void prep_half(const float* __restrict__ src, _Float16* __restrict__ dst) {
    size_t i8 = ((size_t)blockIdx.x * 256 + threadIdx.x) * 8;
    f32x4 a = *(const f32x4*)(src + i8);
    f32x4 b = *(const f32x4*)(src + i8 + 4);
    f16x8 h;
    h[0] = (_Float16)a[0]; h[1] = (_Float16)a[1];
    h[2] = (_Float16)a[2]; h[3] = (_Float16)a[3];
    h[4] = (_Float16)b[0]; h[5] = (_Float16)b[1];
    h[6] = (_Float16)b[2]; h[7] = (_Float16)b[3];
    *(f16x8*)(dst + i8) = h;
}

// ---- prep: V [bh][k][d] fp32  ->  V^T fp16 [bh][d][k] ----
__global__ void prep_vt(const float* __restrict__ V, _Float16* __restrict__ vt) {
    __shared__ float tile[64][65];
    const int bh = blockIdx.y;
    const int k0 = blockIdx.x * 64;
    const int t = threadIdx.x;
    {
        int r = t >> 2, c0 = (t & 3) * 16;
        const float* src = V + ((size_t)bh * S_LEN + k0 + r) * D_HEAD + c0;
        #pragma unroll
        for (int i = 0; i < 16; i += 4) {
            f32x4 v = *(const f32x4*)(src + i);
            tile[r][c0 + i + 0] = v[0];
            tile[r][c0 + i + 1] = v[1];
            tile[r][c0 + i + 2] = v[2];
            tile[r][c0 + i + 3] = v[3];
        }
    }
    __syncthreads();
    {
        int d = t >> 2, kc = (t & 3) * 16;
        size_t ob = ((size_t)bh * D_HEAD + d) * S_LEN + k0 + kc;
        #pragma unroll
        for (int half = 0; half < 2; ++half) {
            f16x8 hv;
            #pragma unroll
            for (int i = 0; i < 8; ++i)
                hv[i] = (_Float16)tile[kc + half * 8 + i][d];
            *(f16x8*)(vt + ob + half * 8) = hv;
        }
    }
}

// ============================================================================
// main: two-pass fused attention, log2-domain max-free softmax, all-fp16.
// r14 restored (empirical optimum, 92.9 us): 2-SLOT wave-private p-buffers
// + WQ-PAIR flush (2 instr x 4 rows x 256B runs), 128-row P1 dbuf, counted
// vmcnt + raw s_barrier per iter, 3 blocks/CU.
// ============================================================================
__launch_bounds__(512, 6)
__global__ void attn_main(const float* __restrict__ Q, const int* __restrict__ mask,
                          const float* __restrict__ bias2,
                          const _Float16* __restrict__ kh_g,
                          const _Float16* __restrict__ vt_g,
                          float* __restrict__ outp, float* __restrict__ p_out) {
    __shared__ __align__(16) char smem[53760];
    _Float16* pball = (_Float16*)(smem + 32768);   // 8 x 2 x 640 f16
    float* stats = (float*)(smem + 53248);         // 128 floats

    const int tid = threadIdx.x;
    const int w = tid >> 6, l = tid & 63;
    const int wq = w & 3, wk = w >> 2;
    const int g = l >> 4, lq = l & 15;
    const int r7 = lq & 7;
    const int bid = blockIdx.x;
    const int bh = bid & 15, b = bh >> 2, h = bh & 3;   // bid%8 == bh%8: bh pinned per XCD
    const int q0 = (bid >> 4) * 64;

    const float* Qp = Q + (size_t)bh * (S_LEN * D_HEAD);
    const int* mp = mask + b * S_LEN;
    const _Float16* khp = kh_g + (size_t)bh * (S_LEN * D_HEAD);
    const _Float16* vhp = vt_g + (size_t)bh * (S_LEN * D_HEAD);

    // ---- stage Q -> f16 (swizzled ds_write) at smem[0..8K) ----
    _Float16* qarea = (_Float16*)smem;
    {
        int sr = tid >> 3, tb = tid & 7;
        const float* src = Qp + (size_t)(q0 + sr) * D_HEAD + tb * 8;
        f32x4 a = *(const f32x4*)src;
        f32x4 c = *(const f32x4*)(src + 4);
        f16x8 hv;
        hv[0] = (_Float16)a[0]; hv[1] = (_Float16)a[1];
        hv[2] = (_Float16)a[2]; hv[3] = (_Float16)a[3];
        hv[4] = (_Float16)c[0]; hv[5] = (_Float16)c[1];
        hv[6] = (_Float16)c[2]; hv[7] = (_Float16)c[3];
        *(f16x8*)(qarea + sr * 64 + ((tb ^ (sr & 7)) * 8)) = hv;
    }
    __syncthreads();
    f16x8 qf[2];
    const int qrow = 16 * wq + lq;
    #pragma unroll
    for (int c = 0; c < 2; ++c)
        qf[c] = *(const f16x8*)(qarea + qrow * 64 + ((4 * c + g) ^ r7) * 8);
    __syncthreads();   // all Q reads done before staging overwrites [0..8K)

    const int qq = q0 + qrow;

    // hoisted staging geometry
    const int rr3 = tid >> 3;                       // chunk row 0..63
    const int ub0 = (((tid & 7) ^ (rr3 & 7)) * 8);  // swizzled 8-elem block
    // pass-1 prologue: stage K rows 0..127 -> smem[0..16K)
    const _Float16* s1a = khp + (size_t)rr3 * 64 + ub0;
    gl_lds16(s1a, smem + tid * 16);
    gl_lds16(s1a + 4096, smem + 8192 + tid * 16);
    __syncthreads();   // full drain, once

    // ================= PASS 1: l = sum(2^s2), K-tile 128, 16 iters =================
    const int* mP1 = mp + 64 * wk + 4 * g;
    const float* bP1 = bias2 + h * 4096 + 2047 - qq + 64 * wk + 4 * g;
    float lsum = 0.0f;
    for (int t = 0; t < 16; ++t) {
        const char* kb = smem + (t & 1) * 16384;
        int4 mv[4]; f32x4 bv[4];
        #pragma unroll
        for (int t2 = 0; t2 < 4; ++t2) {
            mv[t2] = *(const int4*)(mP1 + 16 * t2);
            bv[t2] = *(const f32x4*)(bP1 + 16 * t2);
        }
        if (t < 15) {
            s1a += 8192;
            char* nb = smem + ((t + 1) & 1) * 16384 + tid * 16;
            gl_lds16(s1a, nb);
            gl_lds16(s1a + 4096, nb + 8192);
        }
        __builtin_amdgcn_sched_barrier(0);
        #pragma unroll
        for (int t2 = 0; t2 < 4; ++t2) {
            const int krow = 64 * wk + 16 * t2 + lq;
            f32x4 acc = {0.f, 0.f, 0.f, 0.f};
            #pragma unroll
            for (int c = 0; c < 2; ++c) {
                f16x8 af = *(const f16x8*)(kb + krow * 128 + ((4 * c + g) ^ r7) * 16);
                acc = __builtin_amdgcn_mfma_f32_16x16x32_f16(af, qf[c], acc, 0, 0, 0);
            }
            float s0 = mv[t2].x ? fmaf(acc[0], C2, bv[t2][0]) : -1e9f;
            float s1 = mv[t2].y ? fmaf(acc[1], C2, bv[t2][1]) : -1e9f;
            float s2 = mv[t2].z ? fmaf(acc[2], C2, bv[t2][2]) : -1e9f;
            float s3 = mv[t2].w ? fmaf(acc[3], C2, bv[t2][3]) : -1e9f;
            lsum += exp2v(s0) + exp2v(s1) + exp2v(s2) + exp2v(s3);
        }
        mP1 += 128; bP1 += 128;
        asm volatile("s_waitcnt vmcnt(0)" ::: "memory");
        __builtin_amdgcn_sched_barrier(0);
        __builtin_amdgcn_s_barrier();
        __builtin_amdgcn_sched_barrier(0);
    }
    lsum += __shfl_xor(lsum, 16);
    lsum += __shfl_xor(lsum, 32);
    if (g == 0) stats[wk * 64 + qrow] = lsum;

    // ---- pass-2 staging pointers + prologue (buf0: K64, V64) ----
    const _Float16* sKh = khp + (size_t)rr3 * 64 + ub0;
    const _Float16* sVh = vhp + (size_t)rr3 * 2048 + ub0;
    gl_lds16(sKh, smem + tid * 16);
    gl_lds16(sVh, smem + 8192 + tid * 16);
    __syncthreads();   // stats visible + buf0 staged (full drain, once)
    float lr2q;
    {
        float L = stats[qrow] + stats[64 + qrow];
        float lg; asm("v_log_f32 %0, %1" : "=v"(lg) : "v"(L));
        lr2q = -lg;    // p = 2^(s2 + lr2q)
    }

    // ================= PASS 2: 2-slot p, wq-pair 256B-run flush =================
    f32x4 acco[4] = {{0.f,0.f,0.f,0.f},{0.f,0.f,0.f,0.f},{0.f,0.f,0.f,0.f},{0.f,0.f,0.f,0.f}};
    const int* mP = mp + 32 * wk + 4 * g;
    const float* bP = bias2 + h * 4096 + 2047 - qq + 32 * wk + 4 * g;
    const int kAoff0 = (32 * wk + lq) * 128;               // K frag byte base (+t2*2048)
    const int voffb = lq * 128 + ((4 * wk + g) ^ r7) * 16; // V frag byte base (+n*2048)
    // p-buffer (2 slots per wave): base + slot*640
    _Float16* pwr = pball + w * 1280 + lq * 40 + g * 4;          // + slot*640 + 16*t2
    const _Float16* prd = pball + w * 1280 + lq * 40 + g * 8;    // + slot*640
    // flush: lane's k-half picks the (wq, h2) buffer; 2 stores x (4 rows x 256B)
    const _Float16* flb = pball + ((((l >> 3) & 1) * 4 + wq) * 1280)
                        + (8 * wk + (l >> 4)) * 40 + (l & 7) * 4;   // + ps*640 + i*160
    float* pF = p_out + (size_t)bh * (S_LEN * S_LEN)
              + (size_t)(q0 + 16 * wq + 8 * wk + (l >> 4)) * S_LEN + (l & 15) * 4;

    for (int t = 0; t < 32; ++t) {
        const int cb = (t & 1) * 16384;
        const int cs = (t & 1) * 640;          // current slot
        int4 mv[2]; f32x4 bv[2];
        #pragma unroll
        for (int t2 = 0; t2 < 2; ++t2) {
            mv[t2] = *(const int4*)(mP + 16 * t2);
            bv[t2] = *(const f32x4*)(bP + 16 * t2);
        }
        if (t < 31) {
            sKh += 4096; sVh += 64;
            char* d0 = smem + ((t + 1) & 1) * 16384 + tid * 16;
            gl_lds16(sKh, d0);
            gl_lds16(sVh, d0 + 8192);
        }
        // flush tile t-1 from slot cs^640 (stores NEWEST in queue; prev-iter
        // barrier + lgkmcnt(0) made all waves' p visible)
        if (t > 0) {
            const int ps = cs ^ 640;
            #pragma unroll
            for (int i = 0; i < 2; ++i) {
                f16x4v v = *(const f16x4v*)(flb + ps + i * 160);
                f32x4 wv;
                wv[0] = (float)v[0]; wv[1] = (float)v[1];
                wv[2] = (float)v[2]; wv[3] = (float)v[3];
                *(f32x4*)(pF + (size_t)(4 * i) * S_LEN) = wv;
            }
            pF += 64;
        }
        __builtin_amdgcn_sched_barrier(0);
        #pragma unroll
        for (int t2 = 0; t2 < 2; ++t2) {
            const char* kbase = smem + cb + kAoff0 + t2 * 2048;
            f32x4 acc = {0.f, 0.f, 0.f, 0.f};
            #pragma unroll
            for (int c = 0; c < 2; ++c) {
                f16x8 ah = *(const f16x8*)(kbase + ((4 * c + g) ^ r7) * 16);
                acc = __builtin_amdgcn_mfma_f32_16x16x32_f16(ah, qf[c], acc, 0, 0, 0);
            }
            float p0 = exp2v(mv[t2].x ? fmaf(acc[0], C2, bv[t2][0]) + lr2q : -1e9f);
            float p1 = exp2v(mv[t2].y ? fmaf(acc[1], C2, bv[t2][1]) + lr2q : -1e9f);
            float p2 = exp2v(mv[t2].z ? fmaf(acc[2], C2, bv[t2][2]) + lr2q : -1e9f);
            float p3 = exp2v(mv[t2].w ? fmaf(acc[3], C2, bv[t2][3]) + lr2q : -1e9f);
            f16x4v ph;
            ph[0] = (_Float16)p0; ph[1] = (_Float16)p1;
            ph[2] = (_Float16)p2; ph[3] = (_Float16)p3;
            *(f16x4v*)(pwr + cs + 16 * t2) = ph;   // p -> own slot
        }
        // PV: A = P [16q x 32k] (own slot), B = V^T f16
        const f16x8 pf = *(const f16x8*)(prd + cs);
        #pragma unroll
        for (int n = 0; n < 4; ++n) {
            const f16x8 bhf = *(const f16x8*)(smem + cb + 8192 + voffb + n * 2048);
            acco[n] = __builtin_amdgcn_mfma_f32_16x16x32_f16(pf, bhf, acco[n], 0, 0, 0);
        }
        mP += 64; bP += 64;
        // end-of-iter: staging retired (2 flush stores ride); lgkm drained so
        // next iter's cross-wave flush reads see this iter's p
        asm volatile("s_waitcnt vmcnt(2) lgkmcnt(0)" ::: "memory");
        __builtin_amdgcn_sched_barrier(0);
        __builtin_amdgcn_s_barrier();
        __builtin_amdgcn_sched_barrier(0);
    }
    // final flush: tile 31, slot 1 (last end-of-iter barrier made p visible)
    {
        #pragma unroll
        for (int i = 0; i < 2; ++i) {
            f16x4v v = *(const f16x4v*)(flb + 640 + i * 160);
            f32x4 wv;
            wv[0] = (float)v[0]; wv[1] = (float)v[1];
            wv[2] = (float)v[2]; wv[3] = (float)v[3];
            *(f32x4*)(pF + (size_t)(4 * i) * S_LEN) = wv;
        }
    }

    // ---- reduce the two wk halves (stage area is dead) and store out ----
    float* ored = (float*)smem;    // [64 q][64 d]
    __syncthreads();
    if (wk == 1) {
        #pragma unroll
        for (int n = 0; n < 4; ++n)
            #pragma unroll
            for (int r = 0; r < 4; ++r)
                ored[(wq * 16 + 4 * g + r) * 64 + 16 * n + lq] = acco[n][r];
    }
    __syncthreads();
    if (wk == 0) {
        #pragma unroll
        for (int n = 0; n < 4; ++n) {
            #pragma unroll
            for (int r = 0; r < 4; ++r) {
                float v = acco[n][r] + ored[(wq * 16 + 4 * g + r) * 64 + 16 * n + lq];
                outp[((size_t)bh * S_LEN + q0 + 16 * wq + 4 * g + r) * D_HEAD + 16 * n + lq] = v;
            }
        }
    }
}

extern "C" void kernel_launch(void* const* d_in, const int* in_sizes, int n_in,
                              void* d_out, int out_size, void* d_ws, size_t ws_size,
                              hipStream_t stream) {
    const float* Q = (const float*)d_in[0];
    const float* K = (const float*)d_in[1];
    const float* V = (const float*)d_in[2];
    const int* mask = (const int*)d_in[3];
    const float* table = (const float*)d_in[4];

    float* outp = (float*)d_out;
    float* p_out = outp + (size_t)4 * 4 * 2048 * 64;   // out first, then p_attn

    float* bias_d = (float*)d_ws;                                   // 64 KB
    _Float16* kh = (_Float16*)((char*)d_ws + 65536);                // 4 MB
    _Float16* vt = kh + (size_t)16 * S_LEN * D_HEAD;                // 4 MB

    prep_bias<<<16, 256, 0, stream>>>(table, bias_d);
    prep_half<<<1024, 256, 0, stream>>>(K, kh);
    prep_vt<<<dim3(32, 16), 256, 0, stream>>>(V, vt);
    attn_main<<<512, 512, 0, stream>>>(Q, mask, bias_d, kh, vt, outp, p_out);
}